// Round 1
// baseline (27.044 us; speedup 1.0000x reference)
//
#include <hip/hip_runtime.h>

// PadMaskedSequence: per batch row, compact x rows where mask is true
// (stable order), right-pad with 0.0, and emit lens = popcount(mask row).
// Outputs concatenated flat in d_out: x_ [B*T*D] f32, then lens [B] written
// as float (harness reads whole buffer as f32).

#define SCAN_THREADS 1024

__global__ void pad_masked_scan_kernel(const int* __restrict__ mask,
                                       int* __restrict__ idx,
                                       int* __restrict__ lens_i,
                                       float* __restrict__ lens_f,
                                       int T) {
    const int b = blockIdx.x;
    const int tid = threadIdx.x;
    const int per = T / SCAN_THREADS;  // 4 for T=4096
    const int base = b * T + tid * per;

    int m[8];
    int local = 0;
    #pragma unroll
    for (int i = 0; i < 8; ++i) {
        if (i < per) {
            m[i] = mask[base + i];
            local += (m[i] != 0);
        }
    }

    __shared__ int s[SCAN_THREADS];
    s[tid] = local;
    __syncthreads();
    // Hillis-Steele inclusive scan over thread sums.
    for (int off = 1; off < SCAN_THREADS; off <<= 1) {
        int v = (tid >= off) ? s[tid - off] : 0;
        __syncthreads();
        s[tid] += v;
        __syncthreads();
    }
    int run = s[tid] - local;  // exclusive prefix for this thread's chunk
    #pragma unroll
    for (int i = 0; i < 8; ++i) {
        if (i < per && m[i] != 0) {
            idx[b * T + run] = tid * per + i;
            ++run;
        }
    }
    if (tid == SCAN_THREADS - 1) {
        lens_i[b] = s[tid];
        lens_f[b] = (float)s[tid];
    }
}

// One wave (64 threads) per output row: copy 256 floats as 64 float4s,
// or write zeros for padding rows.
__global__ void pad_masked_gather_kernel(const float* __restrict__ x,
                                         const int* __restrict__ idx,
                                         const int* __restrict__ lens,
                                         float* __restrict__ out,
                                         int T, int D4) {
    const int j = blockIdx.x;   // output row within batch
    const int b = blockIdx.y;   // batch
    const int tid = threadIdx.x;  // 0..D4-1

    const int L = lens[b];
    float4 v = make_float4(0.f, 0.f, 0.f, 0.f);
    if (j < L) {
        const int src = idx[b * T + j];
        v = reinterpret_cast<const float4*>(x)[(size_t)(b * T + src) * D4 + tid];
    }
    reinterpret_cast<float4*>(out)[(size_t)(b * T + j) * D4 + tid] = v;
}

extern "C" void kernel_launch(void* const* d_in, const int* in_sizes, int n_in,
                              void* d_out, int out_size, void* d_ws, size_t ws_size,
                              hipStream_t stream) {
    const float* x = (const float*)d_in[0];
    const int* mask = (const int*)d_in[1];

    const int Nx = in_sizes[0];        // B*T*D
    const int BT = in_sizes[1];        // B*T
    const int B = out_size - Nx;       // lens elements appended after x_
    const int T = BT / B;
    const int D = Nx / BT;

    int* idx = (int*)d_ws;             // [B*T]
    int* lens_i = idx + BT;            // [B]
    float* out = (float*)d_out;
    float* lens_f = out + (size_t)Nx;  // lens written as float values

    pad_masked_scan_kernel<<<B, SCAN_THREADS, 0, stream>>>(mask, idx, lens_i, lens_f, T);
    pad_masked_gather_kernel<<<dim3(T, B), D / 4, 0, stream>>>(x, idx, lens_i, out, T, D / 4);
}

// Round 2
// 26.185 us; speedup vs baseline: 1.0328x; 1.0328x over previous
//
#include <hip/hip_runtime.h>

// PadMaskedSequence: per batch row, compact x rows where mask is true
// (stable order), right-pad with 0.0, and emit lens = popcount(mask row).
// d_out layout: x_ [B*T*D] f32, then lens [B] as float.

#define SCAN_THREADS 1024

// One block per batch row. Shuffle-based hierarchical scan:
// wave-level inclusive scan via __shfl_up (no barriers), then one barrier to
// combine the 16 wave sums. Assumes T % (4*SCAN_THREADS) == 0.
__global__ void pad_masked_scan_kernel(const int* __restrict__ mask,
                                       int* __restrict__ idx,
                                       int* __restrict__ lens_i,
                                       float* __restrict__ lens_f,
                                       int T) {
    const int b = blockIdx.x;
    const int tid = threadIdx.x;
    const int lane = tid & 63;
    const int wave = tid >> 6;          // 0..15
    const int chunkElems = 4 * SCAN_THREADS;
    const int nChunks = T / chunkElems; // 1 for T=4096

    __shared__ int wsum[SCAN_THREADS / 64];
    int rowTotal = 0;

    for (int c = 0; c < nChunks; ++c) {
        const int4 mv = reinterpret_cast<const int4*>(mask + b * T + c * chunkElems)[tid];
        int m0 = (mv.x != 0), m1 = (mv.y != 0), m2 = (mv.z != 0), m3 = (mv.w != 0);
        const int local = m0 + m1 + m2 + m3;

        // Wave-inclusive scan of per-thread counts (6 shuffle steps).
        int incl = local;
        #pragma unroll
        for (int off = 1; off < 64; off <<= 1) {
            int v = __shfl_up(incl, off);
            if (lane >= off) incl += v;
        }
        if (lane == 63) wsum[wave] = incl;
        __syncthreads();
        // Prefix over the 16 wave sums (broadcast LDS reads).
        int woff = rowTotal;
        int chunkTotal = 0;
        #pragma unroll
        for (int w = 0; w < SCAN_THREADS / 64; ++w) {
            int s = wsum[w];
            if (w < wave) woff += s;
            chunkTotal += s;
        }
        int pos = woff + incl - local;  // exclusive prefix for this thread
        const int base = c * chunkElems + tid * 4;
        if (m0) idx[b * T + pos++] = base + 0;
        if (m1) idx[b * T + pos++] = base + 1;
        if (m2) idx[b * T + pos++] = base + 2;
        if (m3) idx[b * T + pos++] = base + 3;
        rowTotal += chunkTotal;
        if (nChunks > 1) __syncthreads();  // protect wsum reuse
    }

    if (tid == 0) {
        lens_i[b] = rowTotal;
        lens_f[b] = (float)rowTotal;
    }
}

// 256 threads = 4 rows per block, one wave (64 lanes) per output row;
// each lane moves one float4 (D = 256 floats = 64 float4s per row).
__global__ void pad_masked_gather_kernel(const float* __restrict__ x,
                                         const int* __restrict__ idx,
                                         const int* __restrict__ lens,
                                         float* __restrict__ out,
                                         int T, int D4) {
    const int b = blockIdx.y;
    const int rowsPerBlock = blockDim.x / D4;
    const int j = blockIdx.x * rowsPerBlock + threadIdx.x / D4;
    const int t = threadIdx.x % D4;

    const int L = lens[b];
    float4 v = make_float4(0.f, 0.f, 0.f, 0.f);
    if (j < L) {
        const int src = idx[b * T + j];
        v = reinterpret_cast<const float4*>(x)[(size_t)(b * T + src) * D4 + t];
    }
    reinterpret_cast<float4*>(out)[(size_t)(b * T + j) * D4 + t] = v;
}

extern "C" void kernel_launch(void* const* d_in, const int* in_sizes, int n_in,
                              void* d_out, int out_size, void* d_ws, size_t ws_size,
                              hipStream_t stream) {
    const float* x = (const float*)d_in[0];
    const int* mask = (const int*)d_in[1];

    const int Nx = in_sizes[0];        // B*T*D
    const int BT = in_sizes[1];        // B*T
    const int B = out_size - Nx;       // lens elements appended after x_
    const int T = BT / B;
    const int D = Nx / BT;
    const int D4 = D / 4;

    int* idx = (int*)d_ws;             // [B*T]
    int* lens_i = idx + BT;            // [B]
    float* out = (float*)d_out;
    float* lens_f = out + (size_t)Nx;  // lens as float values

    pad_masked_scan_kernel<<<B, SCAN_THREADS, 0, stream>>>(mask, idx, lens_i, lens_f, T);

    const int rowsPerBlock = 256 / D4;  // 4 for D=256
    pad_masked_gather_kernel<<<dim3(T / rowsPerBlock, B), 256, 0, stream>>>(
        x, idx, lens_i, out, T, D4);
}

// Round 3
// 22.232 us; speedup vs baseline: 1.2165x; 1.1778x over previous
//
#include <hip/hip_runtime.h>

// PadMaskedSequence, fully fused single kernel.
// d_out layout: x_ [B*T*D] f32, then lens [B] as float.
//
// Grid: (T/ROWS, B, 2). z=0: scatter blocks (copy selected rows to their
// compacted position). z=1: zero blocks (pad rows >= lens with 0).
// Each block independently recomputes the mask prefix it needs from the
// L2-resident mask row (16 KiB/batch) -- no inter-kernel dependency, no idx
// array, no inter-block communication.

#define BLK 256
#define ROWS 64  // rows handled per block

__global__ __launch_bounds__(BLK) void pad_masked_fused(
    const float* __restrict__ x,
    const int* __restrict__ mask,
    float* __restrict__ out,
    float* __restrict__ lens_f,
    int T, int D4) {

    const int c = blockIdx.x;          // chunk of ROWS rows
    const int b = blockIdx.y;          // batch
    const bool zeroPhase = (blockIdx.z != 0);
    const int tid = threadIdx.x;
    const int lane = tid & 63;
    const int wave = tid >> 6;         // 0..3

    const int* mrow = mask + (size_t)b * T;

    // ---- popcount of mask[b][0:limit) ----
    // scatter: limit = c*ROWS  (exclusive prefix -> output base offset)
    // zero:    limit = T       (full row popcount -> lens)
    const int limit = zeroPhase ? T : c * ROWS;
    int partial = 0;
    for (int base = tid * 4; base < limit; base += BLK * 4) {
        const int4 mv = *reinterpret_cast<const int4*>(mrow + base);
        partial += (mv.x != 0) + (mv.y != 0) + (mv.z != 0) + (mv.w != 0);
    }
    // block reduction (wave shuffle + 4-entry LDS combine)
    __shared__ int wred[BLK / 64];
    int s = partial;
    #pragma unroll
    for (int off = 32; off; off >>= 1) s += __shfl_xor(s, off);
    if (lane == 0) wred[wave] = s;
    __syncthreads();
    const int P = wred[0] + wred[1] + wred[2] + wred[3];

    if (zeroPhase) {
        const int L = P;  // lens[b]
        if (c == 0 && tid == 0) lens_f[b] = (float)L;
        const int j0 = c * ROWS;
        if (j0 + ROWS <= L) return;  // chunk entirely data rows
        float4* orow = reinterpret_cast<float4*>(out) + ((size_t)b * T + j0) * (size_t)D4;
        const float4 z = make_float4(0.f, 0.f, 0.f, 0.f);
        for (int r = wave; r < ROWS; r += BLK / 64) {
            if (j0 + r >= L) {
                for (int t = lane; t < D4; t += 64)
                    orow[(size_t)r * D4 + t] = z;
            }
        }
        return;
    }

    // ---- scatter phase: ranks within this chunk (wave 0 computes) ----
    __shared__ int selsh[ROWS];
    __shared__ int ranksh[ROWS];
    if (wave == 0) {
        const int m = (mrow[c * ROWS + lane] != 0);
        int incl = m;
        #pragma unroll
        for (int off = 1; off < 64; off <<= 1) {
            int v = __shfl_up(incl, off);
            if (lane >= off) incl += v;
        }
        selsh[lane] = m;
        ranksh[lane] = incl - m;  // exclusive rank
    }
    __syncthreads();

    const float4* xrow = reinterpret_cast<const float4*>(x) +
                         ((size_t)b * T + (size_t)c * ROWS) * (size_t)D4;
    float4* obase = reinterpret_cast<float4*>(out) + (size_t)b * T * (size_t)D4;
    for (int r = wave; r < ROWS; r += BLK / 64) {
        if (selsh[r]) {
            const size_t j = (size_t)(P + ranksh[r]);
            for (int t = lane; t < D4; t += 64)
                obase[j * D4 + t] = xrow[(size_t)r * D4 + t];
        }
    }
}

extern "C" void kernel_launch(void* const* d_in, const int* in_sizes, int n_in,
                              void* d_out, int out_size, void* d_ws, size_t ws_size,
                              hipStream_t stream) {
    const float* x = (const float*)d_in[0];
    const int* mask = (const int*)d_in[1];

    const int Nx = in_sizes[0];   // B*T*D
    const int BT = in_sizes[1];   // B*T
    const int B = out_size - Nx;  // lens appended after x_
    const int T = BT / B;
    const int D = Nx / BT;
    const int D4 = D / 4;

    float* out = (float*)d_out;
    float* lens_f = out + (size_t)Nx;

    dim3 grid(T / ROWS, B, 2);
    pad_masked_fused<<<grid, BLK, 0, stream>>>(x, mask, out, lens_f, T, D4);
}